// Round 3
// baseline (630.553 us; speedup 1.0000x reference)
//
#include <hip/hip_runtime.h>
#include <stdint.h>

#define N_TOK 4096
#define QDIM  1024
#define CDIM  1024
#define NH    8
#define DH    64
#define INNER 512
#define BATCH 2
#define N1    4097   // keys incl. background row
#define N1P   4128   // padded to /32
#define NJB   129    // N1P/32
#define VROWS 80     // 64 V dims + mask row + 15 unused
#define PSTR  21     // LDS P row stride in dwords (conflict-free)

typedef __attribute__((ext_vector_type(8))) short short8;
typedef __attribute__((ext_vector_type(4))) float f32x4;
typedef __attribute__((ext_vector_type(4))) uint32_t u32x4;

__device__ __forceinline__ short f2bf(float f) {
    union { float f; uint32_t u; } x; x.f = f;
    uint32_t r = x.u + 0x7fffu + ((x.u >> 16) & 1u);   // RNE
    return (short)(r >> 16);
}

__device__ __forceinline__ void async_copy16(void* lds, const void* g) {
    __builtin_amdgcn_global_load_lds(
        (const __attribute__((address_space(1))) void*)g,
        (__attribute__((address_space(3))) void*)lds, 16, 0, 0);
}

// ---------------- cast fp32 -> bf16 for x and ctx in one dispatch ----------------
__global__ __launch_bounds__(256) void cast2_bf16_kernel(
        const float* __restrict__ a, const float* __restrict__ b,
        short* __restrict__ da, short* __restrict__ db, int n4) {
    int i = blockIdx.x * 256 + threadIdx.x;
    bool first = i < n4;
    const float* s = first ? a : b;
    short* d = first ? da : db;
    int j = first ? i : i - n4;
    float4 v = ((const float4*)s)[j];
    ((short4*)d)[j] = make_short4(f2bf(v.x), f2bf(v.y), f2bf(v.z), f2bf(v.w));
}

// ------ weight transpose-cast: W[K][N] f32 -> Wt[N][K] bf16, optional scale ------
__global__ __launch_bounds__(256) void transpose_cast_kernel(
        const float* __restrict__ W, short* __restrict__ Wt, int K, int N,
        float scale) {
    __shared__ float tile[32][33];
    int n0 = blockIdx.x * 32, k0 = blockIdx.y * 32;
    int tx = threadIdx.x & 31, ty = threadIdx.x >> 5;       // ty 0..7
    for (int r = ty; r < 32; r += 8)
        tile[r][tx] = W[(size_t)(k0 + r) * N + n0 + tx];
    __syncthreads();
    for (int r = ty; r < 32; r += 8)
        Wt[(size_t)(n0 + r) * K + k0 + tx] = f2bf(tile[tx][r] * scale);
}

// ---------------- pooled mean stage 1: partial sums over 128-row chunks ----------------
__global__ __launch_bounds__(256) void pool_partial_kernel(
        const float* __restrict__ x, float* __restrict__ part) {
    int b = blockIdx.y, c = blockIdx.x;                     // c 0..31
    int t = threadIdx.x;
    float s0 = 0.f, s1 = 0.f, s2 = 0.f, s3 = 0.f;
    const float* xp = x + ((size_t)b * N_TOK + c * 128) * QDIM;
    for (int n = 0; n < 128; n++) {
        const float* row = xp + (size_t)n * QDIM;
        s0 += row[t];
        s1 += row[256 + t];
        s2 += row[512 + t];
        s3 += row[768 + t];
    }
    float* pp = part + ((size_t)b * 32 + c) * QDIM;
    pp[t] = s0; pp[256 + t] = s1; pp[512 + t] = s2; pp[768 + t] = s3;
}

// ------- stage 2: finish mean, fp32 bg projections (1 output/thread), k pads -------
__global__ __launch_bounds__(256) void bg_kernel(
        const float* __restrict__ part, const float* __restrict__ Wkbg,
        const float* __restrict__ Wvbg, short* __restrict__ kb, short* __restrict__ vb) {
    int b = blockIdx.x, jb = blockIdx.y, t = threadIdx.x;   // jb 0..3
    __shared__ float pooled[QDIM];
    for (int d = t; d < QDIM; d += 256) {
        float s = 0.f;
        for (int c = 0; c < 32; c++) s += part[((size_t)b * 32 + c) * QDIM + d];
        pooled[d] = s * (1.f / (float)N_TOK);
    }
    __syncthreads();
    int flat = jb * 256 + t;          // 0..1023
    int matv = flat >> 9;             // 0: k, 1: v
    int o = flat & 511;
    const float* W = matv ? Wvbg : Wkbg;
    float s = 0.f;
    for (int k = 0; k < QDIM; k++) s += pooled[k] * W[(size_t)k * INNER + o];
    int h = o >> 6, d = o & 63;
    short* dst = matv ? vb : kb;
    dst[(((size_t)(b * NH + h)) * N1P + N_TOK) * DH + d] = f2bf(s);
    if (jb == 0) {  // zero padding key rows 4097..4127 (K side must be finite)
        for (int idx = t; idx < NH * 31 * DH; idx += 256) {
            int h2 = idx / (31 * DH);
            int r2 = idx % (31 * DH);
            int j = N_TOK + 1 + r2 / DH;
            int d2 = r2 % DH;
            kb[(((size_t)(b * NH + h2)) * N1P + j) * DH + d2] = 0;
        }
    }
}

// ------- V transpose+permute+mask: [BH][N1P][64] -> tiled [BH][129][80][32] -------
__global__ __launch_bounds__(256) void transpose_v_kernel(
        const short* __restrict__ vin, short* __restrict__ vout,
        const int* __restrict__ mask) {
    __shared__ short tile[32][65];
    __shared__ int mloc[32];
    int bh = blockIdx.z, b = bh >> 3;
    int j0 = blockIdx.x * 32, jb = blockIdx.x;
    int tx = threadIdx.x & 63, ty = threadIdx.x >> 6;       // ty 0..3
    const short* src = vin + (size_t)bh * N1P * DH;
    for (int r = ty; r < 32; r += 4)
        tile[r][tx] = src[(size_t)(j0 + r) * DH + tx];
    if (threadIdx.x < 32) {
        int j = j0 + threadIdx.x;
        mloc[threadIdx.x] = (j < N1) ? mask[b * N1 + j] : 0;
    }
    __syncthreads();
    int tp = threadIdx.x & 31, dy = threadIdx.x >> 5;       // dy 0..7
    int s = (tp >> 1) + ((tp & 1) << 4);                    // sigma(p)
    bool mk = mloc[s] != 0;
    short* dst = vout + ((size_t)bh * NJB + jb) * VROWS * 32;
    for (int d = dy; d < DH; d += 8)
        dst[d * 32 + tp] = mk ? tile[s][d] : (short)0;
    if (dy == 0) dst[64 * 32 + tp] = mk ? (short)0x3F80 : (short)0;  // bf16 1.0
}

// ---------------- fused QKV bf16 MFMA GEMM ----------------
__global__ __launch_bounds__(256) void qkv_gemm_kernel(
        const short* __restrict__ x_bf, const short* __restrict__ c_bf,
        const short* __restrict__ Wqt, const short* __restrict__ Wkvt,
        short* __restrict__ q_bf, short* __restrict__ k_bf, short* __restrict__ v_tmp) {
    __shared__ short As[128 * 32];
    __shared__ short Bs[128 * 32];
    const int t = threadIdx.x;
    const int lane = t & 63, w = t >> 6;
    const int wr = w >> 1, wc = w & 1;
    const int lo = lane & 15, g = lane >> 4;
    const int arow = lane >> 2;
    const int ac8 = (lane & 3) * 8;

    const short *A, *W;
    int m0, n0, which;
    int bid = blockIdx.x;
    if (bid < 256) { A = x_bf; W = Wqt;  m0 = (bid >> 2) * 128; n0 = (bid & 3) * 128; which = 0; }
    else { int i = bid - 256; A = c_bf; W = Wkvt; m0 = (i >> 3) * 128; n0 = (i & 7) * 128;
           which = (n0 < 512) ? 1 : 2; }

    f32x4 acc[4][4] = {};
    for (int k0 = 0; k0 < 1024; k0 += 32) {
        for (int q = 0; q < 2; q++) {
            int seg = w * 2 + q;
            async_copy16(&As[seg * 512], A + (size_t)(m0 + seg * 16 + arow) * 1024 + k0 + ac8);
            async_copy16(&Bs[seg * 512], W + (size_t)(n0 + seg * 16 + arow) * 1024 + k0 + ac8);
        }
        __syncthreads();
        short8 af[4], bfv[4];
        for (int i = 0; i < 4; i++)
            af[i] = *(const short8*)&As[(wr * 64 + i * 16 + lo) * 32 + g * 8];
        for (int j = 0; j < 4; j++)
            bfv[j] = *(const short8*)&Bs[(wc * 64 + j * 16 + lo) * 32 + g * 8];
        for (int i = 0; i < 4; i++)
            for (int j = 0; j < 4; j++)
                acc[i][j] = __builtin_amdgcn_mfma_f32_16x16x32_bf16(af[i], bfv[j], acc[i][j], 0, 0, 0);
        __syncthreads();
    }

    short* dstb = (which == 0) ? q_bf : (which == 1) ? k_bf : v_tmp;
    int coloff = (which == 2) ? 512 : 0;
    size_t rowstride = (which == 0) ? N_TOK : N1P;
    for (int i = 0; i < 4; i++)
        for (int j = 0; j < 4; j++) {
            int row = m0 + wr * 64 + i * 16 + g * 4;
            int col = n0 - coloff + wc * 64 + j * 16 + lo;
            f32x4 v = acc[i][j];
            int h = col >> 6, d = col & 63;
            for (int r = 0; r < 4; r++) {
                int m = row + r;
                int b = m >> 12, ii = m & 4095;
                dstb[(((size_t)(b * NH + h)) * rowstride + ii) * DH + d] = f2bf(v[r]);
            }
        }
}

// ---------------- out-projection GEMM: out = O @ Wot^T + bias (f32) ----------------
__global__ __launch_bounds__(256) void out_gemm_kernel(
        const short* __restrict__ A, const short* __restrict__ Wt,
        float* __restrict__ outf, const float* __restrict__ bias) {
    __shared__ short As[128 * 32];
    __shared__ short Bs[128 * 32];
    const int t = threadIdx.x;
    const int lane = t & 63, w = t >> 6;
    const int wr = w >> 1, wc = w & 1;
    const int lo = lane & 15, g = lane >> 4;
    const int arow = lane >> 2;
    const int ac8 = (lane & 3) * 8;
    const int m0 = blockIdx.x * 128, n0 = blockIdx.y * 128;

    f32x4 acc[4][4] = {};
    for (int k0 = 0; k0 < INNER; k0 += 32) {
        for (int q = 0; q < 2; q++) {
            int seg = w * 2 + q;
            async_copy16(&As[seg * 512], A + (size_t)(m0 + seg * 16 + arow) * INNER + k0 + ac8);
            async_copy16(&Bs[seg * 512], Wt + (size_t)(n0 + seg * 16 + arow) * INNER + k0 + ac8);
        }
        __syncthreads();
        short8 af[4], bfv[4];
        for (int i = 0; i < 4; i++)
            af[i] = *(const short8*)&As[(wr * 64 + i * 16 + lo) * 32 + g * 8];
        for (int j = 0; j < 4; j++)
            bfv[j] = *(const short8*)&Bs[(wc * 64 + j * 16 + lo) * 32 + g * 8];
        for (int i = 0; i < 4; i++)
            for (int j = 0; j < 4; j++)
                acc[i][j] = __builtin_amdgcn_mfma_f32_16x16x32_bf16(af[i], bfv[j], acc[i][j], 0, 0, 0);
        __syncthreads();
    }
    for (int i = 0; i < 4; i++)
        for (int j = 0; j < 4; j++) {
            int row = m0 + wr * 64 + i * 16 + g * 4;
            int col = n0 + wc * 64 + j * 16 + lo;
            f32x4 v = acc[i][j];
            for (int r = 0; r < 4; r++)
                outf[(size_t)(row + r) * QDIM + col] = v[r] + bias[col];
        }
}

// ---------------- flash attention, pipelined exp2 softmax ----------------
// grid (64, 8, 2), 256 threads; wave w owns 16 Q rows. 1-iter software pipeline:
// K[j+1],V[j] prefetched to regs during iter j; P double-buffered in LDS
// (DS pipe is in-order per wave -> no explicit waitcnt needed for RAW/WAR).
#define ATTN_STEP(KC, KN, VN, VP, WB, RB, DO_PV)                               \
  {                                                                            \
    KN[0] = *(const short8*)(kp);                                              \
    KN[1] = *(const short8*)(kp + 32);                                         \
    KN[2] = *(const short8*)(kp + 16 * DH);                                    \
    KN[3] = *(const short8*)(kp + 16 * DH + 32);                               \
    kp += 32 * DH;                                                             \
    VN[0] = *(const short8*)(vp - 512);                                        \
    VN[1] = *(const short8*)(vp);                                              \
    VN[2] = *(const short8*)(vp + 512);                                        \
    VN[3] = *(const short8*)(vp + 1024);                                       \
    VN[4] = *(const short8*)(vp + 1536);                                       \
    vp += VROWS * 32;                                                          \
    f32x4 s0 = __builtin_amdgcn_mfma_f32_16x16x32_bf16(qa0, KC[0], z, 0, 0, 0);\
    s0 = __builtin_amdgcn_mfma_f32_16x16x32_bf16(qa1, KC[1], s0, 0, 0, 0);     \
    f32x4 s1 = __builtin_amdgcn_mfma_f32_16x16x32_bf16(qa0, KC[2], z, 0, 0, 0);\
    s1 = __builtin_amdgcn_mfma_f32_16x16x32_bf16(qa1, KC[3], s1, 0, 0, 0);     \
    uint32_t pr0 = 0, pr1 = 0, pr2 = 0, pr3 = 0;                               \
    if (DO_PV) {                                                               \
      pr0 = RB[rdoff]; pr1 = RB[rdoff + 1];                                    \
      pr2 = RB[rdoff + 2]; pr3 = RB[rdoff + 3];                                \
    }                                                                          \
    _Pragma("unroll")                                                          \
    for (int r = 0; r < 4; r++) {                                              \
      uint32_t u0 = __float_as_uint(__builtin_amdgcn_exp2f(s0[r])) + 0x8000u;  \
      uint32_t u1 = __float_as_uint(__builtin_amdgcn_exp2f(s1[r])) + 0x8000u;  \
      WB[(g * 4 + r) * PSTR + lo] = __builtin_amdgcn_perm(u1, u0, 0x07060302u);\
    }                                                                          \
    if (DO_PV) {                                                               \
      u32x4 prv = {pr0, pr1, pr2, pr3};                                        \
      short8 pa = __builtin_bit_cast(short8, prv);                             \
      o0 = __builtin_amdgcn_mfma_f32_16x16x32_bf16(pa, VP[0], o0, 0, 0, 0);    \
      o1 = __builtin_amdgcn_mfma_f32_16x16x32_bf16(pa, VP[1], o1, 0, 0, 0);    \
      o2 = __builtin_amdgcn_mfma_f32_16x16x32_bf16(pa, VP[2], o2, 0, 0, 0);    \
      o3 = __builtin_amdgcn_mfma_f32_16x16x32_bf16(pa, VP[3], o3, 0, 0, 0);    \
      o4 = __builtin_amdgcn_mfma_f32_16x16x32_bf16(pa, VP[4], o4, 0, 0, 0);    \
    }                                                                          \
  }

__global__ __launch_bounds__(256) void attn_kernel(
        const short* __restrict__ qb,   // [BH][4096][64], scaled by 0.125*log2e via Wq
        const short* __restrict__ kb,   // [BH][N1P][64]
        const short* __restrict__ vtb,  // [BH][129][80][32], permuted, masked, row64=mask
        short* __restrict__ ob) {       // [B*4096][512]
    const int t = threadIdx.x, lane = t & 63, w = t >> 6;
    const int lo = lane & 15, g = lane >> 4;
    const int b = blockIdx.z, h = blockIdx.y;
    const int q0 = blockIdx.x * 64 + w * 16;
    const size_t bh = (size_t)(b * NH + h);

    const short* qp = qb + (bh * N_TOK + q0 + lo) * DH;
    short8 qa0 = *(const short8*)(qp + g * 8);
    short8 qa1 = *(const short8*)(qp + 32 + g * 8);

    const short* kp = kb + bh * N1P * DH + (size_t)lo * DH + g * 8;
    const short* vp = vtb + bh * NJB * VROWS * 32 + (size_t)lo * 32 + g * 8 + 512;

    f32x4 o0 = {}, o1 = {}, o2 = {}, o3 = {}, o4 = {};
    f32x4 z = {};
    __shared__ uint32_t plds[4][2][16 * PSTR];
    uint32_t* b0 = &plds[w][0][0];
    uint32_t* b1 = &plds[w][1][0];
    const int rdoff = lo * PSTR + g * 4;

    short8 kA[4], kB[4], vA[5], vB[5];
    // prologue: K[0] -> kA
    kA[0] = *(const short8*)(kp);
    kA[1] = *(const short8*)(kp + 32);
    kA[2] = *(const short8*)(kp + 16 * DH);
    kA[3] = *(const short8*)(kp + 16 * DH + 32);
    kp += 32 * DH;

    // jb = 0: QK with kA, write P[0]->b0, prefetch K[1]->kB, V[0]->vA
    ATTN_STEP(kA, kB, vA, vB, b0, b1, 0)
    // pairs (1,2),(3,4),...,(127,128)
    for (int it = 0; it < 64; ++it) {
        ATTN_STEP(kB, kA, vB, vA, b1, b0, 1)   // odd jb: P[j]->b1, PV(P[j-1] from b0, vA)
        ATTN_STEP(kA, kB, vA, vB, b0, b1, 1)   // even jb
    }
    // epilogue: PV for jb=128 (P in b0, V[128] in vA)
    {
        uint32_t pr0 = b0[rdoff], pr1 = b0[rdoff + 1];
        uint32_t pr2 = b0[rdoff + 2], pr3 = b0[rdoff + 3];
        u32x4 prv = {pr0, pr1, pr2, pr3};
        short8 pa = __builtin_bit_cast(short8, prv);
        o0 = __builtin_amdgcn_mfma_f32_16x16x32_bf16(pa, vA[0], o0, 0, 0, 0);
        o1 = __builtin_amdgcn_mfma_f32_16x16x32_bf16(pa, vA[1], o1, 0, 0, 0);
        o2 = __builtin_amdgcn_mfma_f32_16x16x32_bf16(pa, vA[2], o2, 0, 0, 0);
        o3 = __builtin_amdgcn_mfma_f32_16x16x32_bf16(pa, vA[3], o3, 0, 0, 0);
        o4 = __builtin_amdgcn_mfma_f32_16x16x32_bf16(pa, vA[4], o4, 0, 0, 0);
    }

    short* op = ob + ((size_t)(b * N_TOK) + q0) * INNER + h * DH;
    for (int r = 0; r < 4; r++) {
        float l = __shfl(o4[r], lane & 48);            // col 0 of frag4 = sum(p*mask)
        float inv = (l > 0.f) ? 1.f / l : 0.f;
        short* o = op + (size_t)(g * 4 + r) * INNER;
        o[lo]      = f2bf(o0[r] * inv);
        o[16 + lo] = f2bf(o1[r] * inv);
        o[32 + lo] = f2bf(o2[r] * inv);
        o[48 + lo] = f2bf(o3[r] * inv);
    }
}

extern "C" void kernel_launch(void* const* d_in, const int* in_sizes, int n_in,
                              void* d_out, int out_size, void* d_ws, size_t ws_size,
                              hipStream_t stream) {
    const float* x    = (const float*)d_in[0];
    const float* ctx  = (const float*)d_in[1];
    const int*   mask = (const int*)d_in[2];
    const float* Wq   = (const float*)d_in[3];
    const float* Wk   = (const float*)d_in[4];
    const float* Wv   = (const float*)d_in[5];
    const float* Wkbg = (const float*)d_in[6];
    const float* Wvbg = (const float*)d_in[7];
    const float* Wout = (const float*)d_in[8];
    const float* bout = (const float*)d_in[9];
    float* out = (float*)d_out;

    char* p = (char*)d_ws;
    auto alloc = [&](size_t b) { char* r = p; p += (b + 255) & ~(size_t)255; return r; };
    short* x_bf  = (short*)alloc((size_t)BATCH * N_TOK * QDIM * 2);
    short* c_bf  = (short*)alloc((size_t)BATCH * N_TOK * CDIM * 2);
    short* Wqt   = (short*)alloc((size_t)INNER * QDIM * 2);
    short* Wkvt  = (short*)alloc((size_t)2 * INNER * CDIM * 2);   // Wk | Wv transposed
    short* Wot   = (short*)alloc((size_t)QDIM * INNER * 2);
    short* q_bf  = (short*)alloc((size_t)BATCH * NH * N_TOK * DH * 2);
    short* k_bf  = (short*)alloc((size_t)BATCH * NH * N1P * DH * 2);
    short* v_tmp = (short*)alloc((size_t)BATCH * NH * N1P * DH * 2);
    short* vt_bf = (short*)alloc((size_t)BATCH * NH * NJB * VROWS * 32 * 2);
    short* o_bf  = (short*)alloc((size_t)BATCH * N_TOK * INNER * 2);
    float* part  = (float*)alloc((size_t)BATCH * 32 * QDIM * 4);

    const float SCALE_Q = 0.125f * 1.4426950408889634f;  // fold scale*log2(e) into Wq

    int n4 = BATCH * N_TOK * QDIM / 4;
    cast2_bf16_kernel<<<(2 * n4 + 255) / 256, 256, 0, stream>>>(x, ctx, x_bf, c_bf, n4);

    transpose_cast_kernel<<<dim3(INNER / 32, QDIM / 32), 256, 0, stream>>>(Wq, Wqt, QDIM, INNER, SCALE_Q);
    transpose_cast_kernel<<<dim3(INNER / 32, CDIM / 32), 256, 0, stream>>>(Wk, Wkvt, CDIM, INNER, 1.f);
    transpose_cast_kernel<<<dim3(INNER / 32, CDIM / 32), 256, 0, stream>>>(Wv, Wkvt + (size_t)INNER * CDIM, CDIM, INNER, 1.f);
    transpose_cast_kernel<<<dim3(QDIM / 32, INNER / 32), 256, 0, stream>>>(Wout, Wot, INNER, QDIM, 1.f);

    pool_partial_kernel<<<dim3(32, BATCH), 256, 0, stream>>>(x, part);

    qkv_gemm_kernel<<<768, 256, 0, stream>>>(x_bf, c_bf, Wqt, Wkvt, q_bf, k_bf, v_tmp);

    bg_kernel<<<dim3(BATCH, 4), 256, 0, stream>>>(part, Wkbg, Wvbg, k_bf, v_tmp);
    transpose_v_kernel<<<dim3(NJB, 1, BATCH * NH), 256, 0, stream>>>(v_tmp, vt_bf, mask);

    attn_kernel<<<dim3(N_TOK / 64, NH, BATCH), 256, 0, stream>>>(q_bf, k_bf, vt_bf, o_bf);

    out_gemm_kernel<<<dim3(64, 8), 256, 0, stream>>>(o_bf, Wot, out, bout);
}

// Round 4
// 628.928 us; speedup vs baseline: 1.0026x; 1.0026x over previous
//
#include <hip/hip_runtime.h>
#include <stdint.h>

#define N_TOK 4096
#define QDIM  1024
#define CDIM  1024
#define NH    8
#define DH    64
#define INNER 512
#define BATCH 2
#define N1    4097   // keys incl. background row
#define N1P   4128   // padded to /32
#define NJB   129    // N1P/32
#define VROWS 80     // 64 V dims + mask row + 15 unused
#define PSTRD 20     // LDS P row stride in dwords (b128-aligned reads, 2-way writes)

typedef __attribute__((ext_vector_type(8))) short short8;
typedef __attribute__((ext_vector_type(4))) float f32x4;
typedef __attribute__((ext_vector_type(4))) uint32_t u32x4;

__device__ __forceinline__ short f2bf(float f) {
    union { float f; uint32_t u; } x; x.f = f;
    uint32_t r = x.u + 0x7fffu + ((x.u >> 16) & 1u);   // RNE
    return (short)(r >> 16);
}

__device__ __forceinline__ void async_copy16(void* lds, const void* g) {
    __builtin_amdgcn_global_load_lds(
        (const __attribute__((address_space(1))) void*)g,
        (__attribute__((address_space(3))) void*)lds, 16, 0, 0);
}

// ---------------- cast fp32 -> bf16 for x and ctx in one dispatch ----------------
__global__ __launch_bounds__(256) void cast2_bf16_kernel(
        const float* __restrict__ a, const float* __restrict__ b,
        short* __restrict__ da, short* __restrict__ db, int n4) {
    int i = blockIdx.x * 256 + threadIdx.x;
    bool first = i < n4;
    const float* s = first ? a : b;
    short* d = first ? da : db;
    int j = first ? i : i - n4;
    float4 v = ((const float4*)s)[j];
    ((short4*)d)[j] = make_short4(f2bf(v.x), f2bf(v.y), f2bf(v.z), f2bf(v.w));
}

// ------ weight transpose-cast: W[K][N] f32 -> Wt[N][K] bf16, optional scale ------
__global__ __launch_bounds__(256) void transpose_cast_kernel(
        const float* __restrict__ W, short* __restrict__ Wt, int K, int N,
        float scale) {
    __shared__ float tile[32][33];
    int n0 = blockIdx.x * 32, k0 = blockIdx.y * 32;
    int tx = threadIdx.x & 31, ty = threadIdx.x >> 5;       // ty 0..7
    for (int r = ty; r < 32; r += 8)
        tile[r][tx] = W[(size_t)(k0 + r) * N + n0 + tx];
    __syncthreads();
    for (int r = ty; r < 32; r += 8)
        Wt[(size_t)(n0 + r) * K + k0 + tx] = f2bf(tile[tx][r] * scale);
}

// ---------------- pooled mean stage 1: partial sums over 128-row chunks ----------------
__global__ __launch_bounds__(256) void pool_partial_kernel(
        const float* __restrict__ x, float* __restrict__ part) {
    int b = blockIdx.y, c = blockIdx.x;                     // c 0..31
    int t = threadIdx.x;
    float s0 = 0.f, s1 = 0.f, s2 = 0.f, s3 = 0.f;
    const float* xp = x + ((size_t)b * N_TOK + c * 128) * QDIM;
    for (int n = 0; n < 128; n++) {
        const float* row = xp + (size_t)n * QDIM;
        s0 += row[t];
        s1 += row[256 + t];
        s2 += row[512 + t];
        s3 += row[768 + t];
    }
    float* pp = part + ((size_t)b * 32 + c) * QDIM;
    pp[t] = s0; pp[256 + t] = s1; pp[512 + t] = s2; pp[768 + t] = s3;
}

// ------- stage 2: finish mean, fp32 bg projections (1 output/thread), k pads -------
__global__ __launch_bounds__(256) void bg_kernel(
        const float* __restrict__ part, const float* __restrict__ Wkbg,
        const float* __restrict__ Wvbg, short* __restrict__ kb, short* __restrict__ vb) {
    int b = blockIdx.x, jb = blockIdx.y, t = threadIdx.x;   // jb 0..3
    __shared__ float pooled[QDIM];
    for (int d = t; d < QDIM; d += 256) {
        float s = 0.f;
        for (int c = 0; c < 32; c++) s += part[((size_t)b * 32 + c) * QDIM + d];
        pooled[d] = s * (1.f / (float)N_TOK);
    }
    __syncthreads();
    int flat = jb * 256 + t;          // 0..1023
    int matv = flat >> 9;             // 0: k, 1: v
    int o = flat & 511;
    const float* W = matv ? Wvbg : Wkbg;
    float s = 0.f;
    for (int k = 0; k < QDIM; k++) s += pooled[k] * W[(size_t)k * INNER + o];
    int h = o >> 6, d = o & 63;
    short* dst = matv ? vb : kb;
    dst[(((size_t)(b * NH + h)) * N1P + N_TOK) * DH + d] = f2bf(s);
    if (jb == 0) {  // zero padding key rows 4097..4127 (K side must be finite)
        for (int idx = t; idx < NH * 31 * DH; idx += 256) {
            int h2 = idx / (31 * DH);
            int r2 = idx % (31 * DH);
            int j = N_TOK + 1 + r2 / DH;
            int d2 = r2 % DH;
            kb[(((size_t)(b * NH + h2)) * N1P + j) * DH + d2] = 0;
        }
    }
}

// ------- V transpose+permute+mask: [BH][N1P][64] -> tiled [BH][129][80][32] -------
__global__ __launch_bounds__(256) void transpose_v_kernel(
        const short* __restrict__ vin, short* __restrict__ vout,
        const int* __restrict__ mask) {
    __shared__ short tile[32][65];
    __shared__ int mloc[32];
    int bh = blockIdx.z, b = bh >> 3;
    int j0 = blockIdx.x * 32, jb = blockIdx.x;
    int tx = threadIdx.x & 63, ty = threadIdx.x >> 6;       // ty 0..3
    const short* src = vin + (size_t)bh * N1P * DH;
    for (int r = ty; r < 32; r += 4)
        tile[r][tx] = src[(size_t)(j0 + r) * DH + tx];
    if (threadIdx.x < 32) {
        int j = j0 + threadIdx.x;
        mloc[threadIdx.x] = (j < N1) ? mask[b * N1 + j] : 0;
    }
    __syncthreads();
    int tp = threadIdx.x & 31, dy = threadIdx.x >> 5;       // dy 0..7
    int s = (tp >> 1) + ((tp & 1) << 4);                    // sigma(p)
    bool mk = mloc[s] != 0;
    short* dst = vout + ((size_t)bh * NJB + jb) * VROWS * 32;
    for (int d = dy; d < DH; d += 8)
        dst[d * 32 + tp] = mk ? tile[s][d] : (short)0;
    if (dy == 0) dst[64 * 32 + tp] = mk ? (short)0x3F80 : (short)0;  // bf16 1.0
}

// ---------------- fused QKV bf16 MFMA GEMM ----------------
__global__ __launch_bounds__(256) void qkv_gemm_kernel(
        const short* __restrict__ x_bf, const short* __restrict__ c_bf,
        const short* __restrict__ Wqt, const short* __restrict__ Wkvt,
        short* __restrict__ q_bf, short* __restrict__ k_bf, short* __restrict__ v_tmp) {
    __shared__ short As[128 * 32];
    __shared__ short Bs[128 * 32];
    const int t = threadIdx.x;
    const int lane = t & 63, w = t >> 6;
    const int wr = w >> 1, wc = w & 1;
    const int lo = lane & 15, g = lane >> 4;
    const int arow = lane >> 2;
    const int ac8 = (lane & 3) * 8;

    const short *A, *W;
    int m0, n0, which;
    int bid = blockIdx.x;
    if (bid < 256) { A = x_bf; W = Wqt;  m0 = (bid >> 2) * 128; n0 = (bid & 3) * 128; which = 0; }
    else { int i = bid - 256; A = c_bf; W = Wkvt; m0 = (i >> 3) * 128; n0 = (i & 7) * 128;
           which = (n0 < 512) ? 1 : 2; }

    f32x4 acc[4][4] = {};
    for (int k0 = 0; k0 < 1024; k0 += 32) {
        for (int q = 0; q < 2; q++) {
            int seg = w * 2 + q;
            async_copy16(&As[seg * 512], A + (size_t)(m0 + seg * 16 + arow) * 1024 + k0 + ac8);
            async_copy16(&Bs[seg * 512], W + (size_t)(n0 + seg * 16 + arow) * 1024 + k0 + ac8);
        }
        __syncthreads();
        short8 af[4], bfv[4];
        for (int i = 0; i < 4; i++)
            af[i] = *(const short8*)&As[(wr * 64 + i * 16 + lo) * 32 + g * 8];
        for (int j = 0; j < 4; j++)
            bfv[j] = *(const short8*)&Bs[(wc * 64 + j * 16 + lo) * 32 + g * 8];
        for (int i = 0; i < 4; i++)
            for (int j = 0; j < 4; j++)
                acc[i][j] = __builtin_amdgcn_mfma_f32_16x16x32_bf16(af[i], bfv[j], acc[i][j], 0, 0, 0);
        __syncthreads();
    }

    short* dstb = (which == 0) ? q_bf : (which == 1) ? k_bf : v_tmp;
    int coloff = (which == 2) ? 512 : 0;
    size_t rowstride = (which == 0) ? N_TOK : N1P;
    for (int i = 0; i < 4; i++)
        for (int j = 0; j < 4; j++) {
            int row = m0 + wr * 64 + i * 16 + g * 4;
            int col = n0 - coloff + wc * 64 + j * 16 + lo;
            f32x4 v = acc[i][j];
            int h = col >> 6, d = col & 63;
            for (int r = 0; r < 4; r++) {
                int m = row + r;
                int b = m >> 12, ii = m & 4095;
                dstb[(((size_t)(b * NH + h)) * rowstride + ii) * DH + d] = f2bf(v[r]);
            }
        }
}

// ---------------- out-projection GEMM: out = O @ Wot^T + bias (f32) ----------------
__global__ __launch_bounds__(256) void out_gemm_kernel(
        const short* __restrict__ A, const short* __restrict__ Wt,
        float* __restrict__ outf, const float* __restrict__ bias) {
    __shared__ short As[128 * 32];
    __shared__ short Bs[128 * 32];
    const int t = threadIdx.x;
    const int lane = t & 63, w = t >> 6;
    const int wr = w >> 1, wc = w & 1;
    const int lo = lane & 15, g = lane >> 4;
    const int arow = lane >> 2;
    const int ac8 = (lane & 3) * 8;
    const int m0 = blockIdx.x * 128, n0 = blockIdx.y * 128;

    f32x4 acc[4][4] = {};
    for (int k0 = 0; k0 < INNER; k0 += 32) {
        for (int q = 0; q < 2; q++) {
            int seg = w * 2 + q;
            async_copy16(&As[seg * 512], A + (size_t)(m0 + seg * 16 + arow) * INNER + k0 + ac8);
            async_copy16(&Bs[seg * 512], Wt + (size_t)(n0 + seg * 16 + arow) * INNER + k0 + ac8);
        }
        __syncthreads();
        short8 af[4], bfv[4];
        for (int i = 0; i < 4; i++)
            af[i] = *(const short8*)&As[(wr * 64 + i * 16 + lo) * 32 + g * 8];
        for (int j = 0; j < 4; j++)
            bfv[j] = *(const short8*)&Bs[(wc * 64 + j * 16 + lo) * 32 + g * 8];
        for (int i = 0; i < 4; i++)
            for (int j = 0; j < 4; j++)
                acc[i][j] = __builtin_amdgcn_mfma_f32_16x16x32_bf16(af[i], bfv[j], acc[i][j], 0, 0, 0);
        __syncthreads();
    }
    for (int i = 0; i < 4; i++)
        for (int j = 0; j < 4; j++) {
            int row = m0 + wr * 64 + i * 16 + g * 4;
            int col = n0 + wc * 64 + j * 16 + lo;
            f32x4 v = acc[i][j];
            for (int r = 0; r < 4; r++)
                outf[(size_t)(row + r) * QDIM + col] = v[r] + bias[col];
        }
}

// ---------------- flash attention, pipelined exp2 softmax ----------------
// 1-D grid 1024 blocks: id&7 = head -> all blocks of head h land on XCD h
// (blockid%8 round-robin heuristic), so K/V (2 heads = 2.4 MB) stay in that
// XCD's 4 MB L2. __launch_bounds__(256,3) gives ~170 VGPRs so the K/V register
// prefetch (72 VGPRs of buffers) survives codegen; wave w owns 16 Q rows.
#define ATTN_STEP(KC, KN, VN, VP, WB, RB, DO_PV)                               \
  {                                                                            \
    KN[0] = *(const short8*)(kp);                                              \
    KN[1] = *(const short8*)(kp + 32);                                         \
    KN[2] = *(const short8*)(kp + 16 * DH);                                    \
    KN[3] = *(const short8*)(kp + 16 * DH + 32);                               \
    kp += 32 * DH;                                                             \
    VN[0] = *(const short8*)(vp - 512);                                        \
    VN[1] = *(const short8*)(vp);                                              \
    VN[2] = *(const short8*)(vp + 512);                                        \
    VN[3] = *(const short8*)(vp + 1024);                                       \
    VN[4] = *(const short8*)(vp + 1536);                                       \
    vp += VROWS * 32;                                                          \
    f32x4 s0 = __builtin_amdgcn_mfma_f32_16x16x32_bf16(qa0, KC[0], z, 0, 0, 0);\
    s0 = __builtin_amdgcn_mfma_f32_16x16x32_bf16(qa1, KC[1], s0, 0, 0, 0);     \
    f32x4 s1 = __builtin_amdgcn_mfma_f32_16x16x32_bf16(qa0, KC[2], z, 0, 0, 0);\
    s1 = __builtin_amdgcn_mfma_f32_16x16x32_bf16(qa1, KC[3], s1, 0, 0, 0);     \
    u32x4 prv = {};                                                            \
    if (DO_PV) prv = *(const u32x4*)&RB[rdoff];                                \
    _Pragma("unroll")                                                          \
    for (int r = 0; r < 4; r++) {                                              \
      uint32_t u0 = __float_as_uint(__builtin_amdgcn_exp2f(s0[r])) + 0x8000u;  \
      uint32_t u1 = __float_as_uint(__builtin_amdgcn_exp2f(s1[r])) + 0x8000u;  \
      WB[(g * 4 + r) * PSTRD + lo] = __builtin_amdgcn_perm(u1, u0, 0x07060302u);\
    }                                                                          \
    if (DO_PV) {                                                               \
      short8 pa = __builtin_bit_cast(short8, prv);                             \
      o0 = __builtin_amdgcn_mfma_f32_16x16x32_bf16(pa, VP[0], o0, 0, 0, 0);    \
      o1 = __builtin_amdgcn_mfma_f32_16x16x32_bf16(pa, VP[1], o1, 0, 0, 0);    \
      o2 = __builtin_amdgcn_mfma_f32_16x16x32_bf16(pa, VP[2], o2, 0, 0, 0);    \
      o3 = __builtin_amdgcn_mfma_f32_16x16x32_bf16(pa, VP[3], o3, 0, 0, 0);    \
      o4 = __builtin_amdgcn_mfma_f32_16x16x32_bf16(pa, VP[4], o4, 0, 0, 0);    \
    }                                                                          \
  }

__global__ __launch_bounds__(256, 3) void attn_kernel(
        const short* __restrict__ qb,   // [BH][4096][64], scaled by 0.125*log2e via Wq
        const short* __restrict__ kb,   // [BH][N1P][64]
        const short* __restrict__ vtb,  // [BH][129][80][32], permuted, masked, row64=mask
        short* __restrict__ ob) {       // [B*4096][512]
    const int t = threadIdx.x, lane = t & 63, w = t >> 6;
    const int lo = lane & 15, g = lane >> 4;
    const int id = blockIdx.x;
    const int h = id & 7, b = (id >> 3) & 1, qt = id >> 4;
    const int q0 = qt * 64 + w * 16;
    const size_t bh = (size_t)(b * NH + h);

    const short* qp = qb + (bh * N_TOK + q0 + lo) * DH;
    short8 qa0 = *(const short8*)(qp + g * 8);
    short8 qa1 = *(const short8*)(qp + 32 + g * 8);

    const short* kp = kb + bh * N1P * DH + (size_t)lo * DH + g * 8;
    const short* vp = vtb + bh * NJB * VROWS * 32 + (size_t)lo * 32 + g * 8 + 512;

    f32x4 o0 = {}, o1 = {}, o2 = {}, o3 = {}, o4 = {};
    f32x4 z = {};
    __shared__ uint32_t plds[4][2][16 * PSTRD];
    uint32_t* b0 = &plds[w][0][0];
    uint32_t* b1 = &plds[w][1][0];
    const int rdoff = lo * PSTRD + g * 4;    // 16B-aligned -> ds_read_b128

    short8 kA[4], kB[4], vA[5], vB[5];
    // prologue: K[0] -> kA
    kA[0] = *(const short8*)(kp);
    kA[1] = *(const short8*)(kp + 32);
    kA[2] = *(const short8*)(kp + 16 * DH);
    kA[3] = *(const short8*)(kp + 16 * DH + 32);
    kp += 32 * DH;

    // jb = 0: QK with kA, write P[0]->b0, prefetch K[1]->kB, V[0]->vA
    ATTN_STEP(kA, kB, vA, vB, b0, b1, 0)
    // pairs (1,2),(3,4),...,(127,128)
    for (int it = 0; it < 64; ++it) {
        ATTN_STEP(kB, kA, vB, vA, b1, b0, 1)   // odd jb: P[j]->b1, PV(P[j-1] from b0, vA)
        ATTN_STEP(kA, kB, vA, vB, b0, b1, 1)   // even jb
    }
    // epilogue: PV for jb=128 (P in b0, V[128] in vA)
    {
        u32x4 prv = *(const u32x4*)&b0[rdoff];
        short8 pa = __builtin_bit_cast(short8, prv);
        o0 = __builtin_amdgcn_mfma_f32_16x16x32_bf16(pa, vA[0], o0, 0, 0, 0);
        o1 = __builtin_amdgcn_mfma_f32_16x16x32_bf16(pa, vA[1], o1, 0, 0, 0);
        o2 = __builtin_amdgcn_mfma_f32_16x16x32_bf16(pa, vA[2], o2, 0, 0, 0);
        o3 = __builtin_amdgcn_mfma_f32_16x16x32_bf16(pa, vA[3], o3, 0, 0, 0);
        o4 = __builtin_amdgcn_mfma_f32_16x16x32_bf16(pa, vA[4], o4, 0, 0, 0);
    }

    short* op = ob + ((size_t)(b * N_TOK) + q0) * INNER + h * DH;
    for (int r = 0; r < 4; r++) {
        float l = __shfl(o4[r], lane & 48);            // col 0 of frag4 = sum(p*mask)
        float inv = (l > 0.f) ? 1.f / l : 0.f;
        short* o = op + (size_t)(g * 4 + r) * INNER;
        o[lo]      = f2bf(o0[r] * inv);
        o[16 + lo] = f2bf(o1[r] * inv);
        o[32 + lo] = f2bf(o2[r] * inv);
        o[48 + lo] = f2bf(o3[r] * inv);
    }
}

extern "C" void kernel_launch(void* const* d_in, const int* in_sizes, int n_in,
                              void* d_out, int out_size, void* d_ws, size_t ws_size,
                              hipStream_t stream) {
    const float* x    = (const float*)d_in[0];
    const float* ctx  = (const float*)d_in[1];
    const int*   mask = (const int*)d_in[2];
    const float* Wq   = (const float*)d_in[3];
    const float* Wk   = (const float*)d_in[4];
    const float* Wv   = (const float*)d_in[5];
    const float* Wkbg = (const float*)d_in[6];
    const float* Wvbg = (const float*)d_in[7];
    const float* Wout = (const float*)d_in[8];
    const float* bout = (const float*)d_in[9];
    float* out = (float*)d_out;

    char* p = (char*)d_ws;
    auto alloc = [&](size_t b) { char* r = p; p += (b + 255) & ~(size_t)255; return r; };
    short* x_bf  = (short*)alloc((size_t)BATCH * N_TOK * QDIM * 2);
    short* c_bf  = (short*)alloc((size_t)BATCH * N_TOK * CDIM * 2);
    short* Wqt   = (short*)alloc((size_t)INNER * QDIM * 2);
    short* Wkvt  = (short*)alloc((size_t)2 * INNER * CDIM * 2);   // Wk | Wv transposed
    short* Wot   = (short*)alloc((size_t)QDIM * INNER * 2);
    short* q_bf  = (short*)alloc((size_t)BATCH * NH * N_TOK * DH * 2);
    short* k_bf  = (short*)alloc((size_t)BATCH * NH * N1P * DH * 2);
    short* v_tmp = (short*)alloc((size_t)BATCH * NH * N1P * DH * 2);
    short* vt_bf = (short*)alloc((size_t)BATCH * NH * NJB * VROWS * 32 * 2);
    short* o_bf  = (short*)alloc((size_t)BATCH * N_TOK * INNER * 2);
    float* part  = (float*)alloc((size_t)BATCH * 32 * QDIM * 4);

    const float SCALE_Q = 0.125f * 1.4426950408889634f;  // fold scale*log2(e) into Wq

    int n4 = BATCH * N_TOK * QDIM / 4;
    cast2_bf16_kernel<<<(2 * n4 + 255) / 256, 256, 0, stream>>>(x, ctx, x_bf, c_bf, n4);

    transpose_cast_kernel<<<dim3(INNER / 32, QDIM / 32), 256, 0, stream>>>(Wq, Wqt, QDIM, INNER, SCALE_Q);
    transpose_cast_kernel<<<dim3(INNER / 32, CDIM / 32), 256, 0, stream>>>(Wk, Wkvt, CDIM, INNER, 1.f);
    transpose_cast_kernel<<<dim3(INNER / 32, CDIM / 32), 256, 0, stream>>>(Wv, Wkvt + (size_t)INNER * CDIM, CDIM, INNER, 1.f);
    transpose_cast_kernel<<<dim3(QDIM / 32, INNER / 32), 256, 0, stream>>>(Wout, Wot, INNER, QDIM, 1.f);

    pool_partial_kernel<<<dim3(32, BATCH), 256, 0, stream>>>(x, part);

    qkv_gemm_kernel<<<768, 256, 0, stream>>>(x_bf, c_bf, Wqt, Wkvt, q_bf, k_bf, v_tmp);

    bg_kernel<<<dim3(BATCH, 4), 256, 0, stream>>>(part, Wkbg, Wvbg, k_bf, v_tmp);
    transpose_v_kernel<<<dim3(NJB, 1, BATCH * NH), 256, 0, stream>>>(v_tmp, vt_bf, mask);

    attn_kernel<<<1024, 256, 0, stream>>>(q_bf, k_bf, vt_bf, o_bf);

    out_gemm_kernel<<<dim3(64, 8), 256, 0, stream>>>(o_bf, Wot, out, bout);
}

// Round 5
// 388.277 us; speedup vs baseline: 1.6240x; 1.6198x over previous
//
#include <hip/hip_runtime.h>
#include <stdint.h>

#define N_TOK 4096
#define QDIM  1024
#define CDIM  1024
#define NH    8
#define DH    64
#define INNER 512
#define BATCH 2
#define N1    4097   // keys incl. background row
#define N1P   4128   // padded to /32
#define NJB   129    // N1P/32
#define VROWS 80     // 64 V dims + mask row + 15 unused
#define PSTRD 20     // LDS P row stride in dwords
#define KTILE_SH 2048  // shorts per K tile: [2][32][32]
#define VTILE_SH 2560  // shorts per V tile: [80][32]

typedef __attribute__((ext_vector_type(8))) short short8;
typedef __attribute__((ext_vector_type(4))) float f32x4;
typedef __attribute__((ext_vector_type(4))) uint32_t u32x4;

__device__ __forceinline__ short f2bf(float f) {
    union { float f; uint32_t u; } x; x.f = f;
    uint32_t r = x.u + 0x7fffu + ((x.u >> 16) & 1u);   // RNE
    return (short)(r >> 16);
}

__device__ __forceinline__ void async_copy16(void* lds, const void* g) {
    __builtin_amdgcn_global_load_lds(
        (const __attribute__((address_space(1))) void*)g,
        (__attribute__((address_space(3))) void*)lds, 16, 0, 0);
}

// ---------------- cast fp32 -> bf16 for x and ctx in one dispatch ----------------
__global__ __launch_bounds__(256) void cast2_bf16_kernel(
        const float* __restrict__ a, const float* __restrict__ b,
        short* __restrict__ da, short* __restrict__ db, int n4) {
    int i = blockIdx.x * 256 + threadIdx.x;
    bool first = i < n4;
    const float* s = first ? a : b;
    short* d = first ? da : db;
    int j = first ? i : i - n4;
    float4 v = ((const float4*)s)[j];
    ((short4*)d)[j] = make_short4(f2bf(v.x), f2bf(v.y), f2bf(v.z), f2bf(v.w));
}

// ------ weight transpose-cast: W[K][N] f32 -> Wt[N][K] bf16, optional scale ------
__global__ __launch_bounds__(256) void transpose_cast_kernel(
        const float* __restrict__ W, short* __restrict__ Wt, int K, int N,
        float scale) {
    __shared__ float tile[32][33];
    int n0 = blockIdx.x * 32, k0 = blockIdx.y * 32;
    int tx = threadIdx.x & 31, ty = threadIdx.x >> 5;       // ty 0..7
    for (int r = ty; r < 32; r += 8)
        tile[r][tx] = W[(size_t)(k0 + r) * N + n0 + tx];
    __syncthreads();
    for (int r = ty; r < 32; r += 8)
        Wt[(size_t)(n0 + r) * K + k0 + tx] = f2bf(tile[tx][r] * scale);
}

// ---------------- pooled mean stage 1: partial sums over 128-row chunks ----------------
__global__ __launch_bounds__(256) void pool_partial_kernel(
        const float* __restrict__ x, float* __restrict__ part) {
    int b = blockIdx.y, c = blockIdx.x;                     // c 0..31
    int t = threadIdx.x;
    float s0 = 0.f, s1 = 0.f, s2 = 0.f, s3 = 0.f;
    const float* xp = x + ((size_t)b * N_TOK + c * 128) * QDIM;
    for (int n = 0; n < 128; n++) {
        const float* row = xp + (size_t)n * QDIM;
        s0 += row[t];
        s1 += row[256 + t];
        s2 += row[512 + t];
        s3 += row[768 + t];
    }
    float* pp = part + ((size_t)b * 32 + c) * QDIM;
    pp[t] = s0; pp[256 + t] = s1; pp[512 + t] = s2; pp[768 + t] = s3;
}

// ------- stage 2: finish mean, fp32 bg projections (1 output/thread), k pads -------
// K is stored tiled: [BH][NJB][2][32][32]; bg row = tile 128, r=0.
__global__ __launch_bounds__(256) void bg_kernel(
        const float* __restrict__ part, const float* __restrict__ Wkbg,
        const float* __restrict__ Wvbg, short* __restrict__ kb, short* __restrict__ vb) {
    int b = blockIdx.x, jb = blockIdx.y, t = threadIdx.x;   // jb 0..3
    __shared__ float pooled[QDIM];
    for (int d = t; d < QDIM; d += 256) {
        float s = 0.f;
        for (int c = 0; c < 32; c++) s += part[((size_t)b * 32 + c) * QDIM + d];
        pooled[d] = s * (1.f / (float)N_TOK);
    }
    __syncthreads();
    int flat = jb * 256 + t;          // 0..1023
    int matv = flat >> 9;             // 0: k, 1: v
    int o = flat & 511;
    const float* W = matv ? Wvbg : Wkbg;
    float s = 0.f;
    for (int k = 0; k < QDIM; k++) s += pooled[k] * W[(size_t)k * INNER + o];
    int h = o >> 6, d = o & 63;
    if (matv) {
        vb[(((size_t)(b * NH + h)) * N1P + N_TOK) * DH + d] = f2bf(s);
    } else {
        kb[((size_t)(b * NH + h)) * NJB * KTILE_SH + 128 * KTILE_SH
           + (d >> 5) * 1024 + (d & 31)] = f2bf(s);
    }
    if (jb == 0) {  // zero padding key rows 4097..4127 (tile 128, r=1..31)
        for (int idx = t; idx < NH * 31 * DH; idx += 256) {
            int h2 = idx / (31 * DH);
            int r2 = idx % (31 * DH);
            int rr = 1 + r2 / DH;
            int d2 = r2 % DH;
            kb[((size_t)(b * NH + h2)) * NJB * KTILE_SH + 128 * KTILE_SH
               + (d2 >> 5) * 1024 + rr * 32 + (d2 & 31)] = 0;
        }
    }
}

// ------- V transpose+permute+mask: [BH][N1P][64] -> tiled [BH][129][80][32] -------
__global__ __launch_bounds__(256) void transpose_v_kernel(
        const short* __restrict__ vin, short* __restrict__ vout,
        const int* __restrict__ mask) {
    __shared__ short tile[32][65];
    __shared__ int mloc[32];
    int bh = blockIdx.z, b = bh >> 3;
    int j0 = blockIdx.x * 32, jb = blockIdx.x;
    int tx = threadIdx.x & 63, ty = threadIdx.x >> 6;       // ty 0..3
    const short* src = vin + (size_t)bh * N1P * DH;
    for (int r = ty; r < 32; r += 4)
        tile[r][tx] = src[(size_t)(j0 + r) * DH + tx];
    if (threadIdx.x < 32) {
        int j = j0 + threadIdx.x;
        mloc[threadIdx.x] = (j < N1) ? mask[b * N1 + j] : 0;
    }
    __syncthreads();
    int tp = threadIdx.x & 31, dy = threadIdx.x >> 5;       // dy 0..7
    int s = (tp >> 1) + ((tp & 1) << 4);                    // sigma(p)
    bool mk = mloc[s] != 0;
    short* dst = vout + ((size_t)bh * NJB + jb) * VTILE_SH;
    for (int d = dy; d < DH; d += 8)
        dst[d * 32 + tp] = mk ? tile[s][d] : (short)0;
    if (dy == 0) dst[64 * 32 + tp] = mk ? (short)0x3F80 : (short)0;  // bf16 1.0
    if (dy == 1)  // zero rows 65..72 partially to keep frag-4 plane defined
        for (int d = 65; d < 80; d++) dst[d * 32 + tp] = 0;
}

// ---------------- fused QKV bf16 MFMA GEMM ----------------
__global__ __launch_bounds__(256) void qkv_gemm_kernel(
        const short* __restrict__ x_bf, const short* __restrict__ c_bf,
        const short* __restrict__ Wqt, const short* __restrict__ Wkvt,
        short* __restrict__ q_bf, short* __restrict__ k_bf, short* __restrict__ v_tmp) {
    __shared__ short As[128 * 32];
    __shared__ short Bs[128 * 32];
    const int t = threadIdx.x;
    const int lane = t & 63, w = t >> 6;
    const int wr = w >> 1, wc = w & 1;
    const int lo = lane & 15, g = lane >> 4;
    const int arow = lane >> 2;
    const int ac8 = (lane & 3) * 8;

    const short *A, *W;
    int m0, n0, which;
    int bid = blockIdx.x;
    if (bid < 256) { A = x_bf; W = Wqt;  m0 = (bid >> 2) * 128; n0 = (bid & 3) * 128; which = 0; }
    else { int i = bid - 256; A = c_bf; W = Wkvt; m0 = (i >> 3) * 128; n0 = (i & 7) * 128;
           which = (n0 < 512) ? 1 : 2; }

    f32x4 acc[4][4] = {};
    for (int k0 = 0; k0 < 1024; k0 += 32) {
        for (int q = 0; q < 2; q++) {
            int seg = w * 2 + q;
            async_copy16(&As[seg * 512], A + (size_t)(m0 + seg * 16 + arow) * 1024 + k0 + ac8);
            async_copy16(&Bs[seg * 512], W + (size_t)(n0 + seg * 16 + arow) * 1024 + k0 + ac8);
        }
        __syncthreads();
        short8 af[4], bfv[4];
        for (int i = 0; i < 4; i++)
            af[i] = *(const short8*)&As[(wr * 64 + i * 16 + lo) * 32 + g * 8];
        for (int j = 0; j < 4; j++)
            bfv[j] = *(const short8*)&Bs[(wc * 64 + j * 16 + lo) * 32 + g * 8];
        for (int i = 0; i < 4; i++)
            for (int j = 0; j < 4; j++)
                acc[i][j] = __builtin_amdgcn_mfma_f32_16x16x32_bf16(af[i], bfv[j], acc[i][j], 0, 0, 0);
        __syncthreads();
    }

    for (int i = 0; i < 4; i++)
        for (int j = 0; j < 4; j++) {
            int row = m0 + wr * 64 + i * 16 + g * 4;
            int col0 = n0 + wc * 64 + j * 16 + lo;
            f32x4 v = acc[i][j];
            for (int r = 0; r < 4; r++) {
                int m = row + r;
                int b = m >> 12, ii = m & 4095;
                if (which == 0) {
                    int h = col0 >> 6, d = col0 & 63;
                    q_bf[(((size_t)(b * NH + h)) * N_TOK + ii) * DH + d] = f2bf(v[r]);
                } else if (which == 1) {
                    int h = col0 >> 6, d = col0 & 63;     // K: tiled layout
                    k_bf[((size_t)(b * NH + h)) * NJB * KTILE_SH + (ii >> 5) * KTILE_SH
                         + (d >> 5) * 1024 + (ii & 31) * 32 + (d & 31)] = f2bf(v[r]);
                } else {
                    int col = col0 - 512;
                    int h = col >> 6, d = col & 63;
                    v_tmp[(((size_t)(b * NH + h)) * N1P + ii) * DH + d] = f2bf(v[r]);
                }
            }
        }
}

// ---------------- out-projection GEMM: out = O @ Wot^T + bias (f32) ----------------
__global__ __launch_bounds__(256) void out_gemm_kernel(
        const short* __restrict__ A, const short* __restrict__ Wt,
        float* __restrict__ outf, const float* __restrict__ bias) {
    __shared__ short As[128 * 32];
    __shared__ short Bs[128 * 32];
    const int t = threadIdx.x;
    const int lane = t & 63, w = t >> 6;
    const int wr = w >> 1, wc = w & 1;
    const int lo = lane & 15, g = lane >> 4;
    const int arow = lane >> 2;
    const int ac8 = (lane & 3) * 8;
    const int m0 = blockIdx.x * 128, n0 = blockIdx.y * 128;

    f32x4 acc[4][4] = {};
    for (int k0 = 0; k0 < INNER; k0 += 32) {
        for (int q = 0; q < 2; q++) {
            int seg = w * 2 + q;
            async_copy16(&As[seg * 512], A + (size_t)(m0 + seg * 16 + arow) * INNER + k0 + ac8);
            async_copy16(&Bs[seg * 512], Wt + (size_t)(n0 + seg * 16 + arow) * INNER + k0 + ac8);
        }
        __syncthreads();
        short8 af[4], bfv[4];
        for (int i = 0; i < 4; i++)
            af[i] = *(const short8*)&As[(wr * 64 + i * 16 + lo) * 32 + g * 8];
        for (int j = 0; j < 4; j++)
            bfv[j] = *(const short8*)&Bs[(wc * 64 + j * 16 + lo) * 32 + g * 8];
        for (int i = 0; i < 4; i++)
            for (int j = 0; j < 4; j++)
                acc[i][j] = __builtin_amdgcn_mfma_f32_16x16x32_bf16(af[i], bfv[j], acc[i][j], 0, 0, 0);
        __syncthreads();
    }
    for (int i = 0; i < 4; i++)
        for (int j = 0; j < 4; j++) {
            int row = m0 + wr * 64 + i * 16 + g * 4;
            int col = n0 + wc * 64 + j * 16 + lo;
            f32x4 v = acc[i][j];
            for (int r = 0; r < 4; r++)
                outf[(size_t)(row + r) * QDIM + col] = v[r] + bias[col];
        }
}

// ---------------- flash attention: LDS-staged K/V, exp2 softmax ----------------
// grid 512 (id&7 = head -> XCD-local K/V), 4 waves; wave owns 32 Q rows.
// Per key-tile (32 keys): 9 global_load_lds DMA instrs stage K(4KB)+V(5KB),
// double-buffered, one __syncthreads per iter. All frag reads via DS pipe.
__global__ __launch_bounds__(256, 2) void attn_kernel(
        const short* __restrict__ qb,   // [BH][4096][64], scaled by 0.125*log2e via Wq
        const short* __restrict__ kb,   // [BH][129][2][32][32] tiled
        const short* __restrict__ vtb,  // [BH][129][80][32], permuted, masked, row64=mask
        short* __restrict__ ob) {       // [B*4096][512]
    const int t = threadIdx.x, lane = t & 63, w = t >> 6;
    const int lo = lane & 15, g = lane >> 4;
    const int id = blockIdx.x;
    const int h = id & 7, b = (id >> 3) & 1, qt = id >> 4;   // qt 0..31
    const int q0 = qt * 128 + w * 32;
    const size_t bh = (size_t)(b * NH + h);

    const short* qp = qb + (bh * N_TOK + q0 + lo) * DH;
    short8 qa[2][2];
    qa[0][0] = *(const short8*)(qp + g * 8);
    qa[0][1] = *(const short8*)(qp + 32 + g * 8);
    qa[1][0] = *(const short8*)(qp + 16 * DH + g * 8);
    qa[1][1] = *(const short8*)(qp + 16 * DH + 32 + g * 8);

    __shared__ short Kl[2][KTILE_SH];
    __shared__ short Vl[2][VTILE_SH];
    __shared__ uint32_t Pl[4][32 * PSTRD];

    const short* ksrc = kb + bh * (size_t)NJB * KTILE_SH + w * 512 + lane * 8;
    const short* vsrc = vtb + bh * (size_t)NJB * VTILE_SH + w * 512 + lane * 8;

    f32x4 o[2][5] = {};
    f32x4 z = {};
    uint32_t* pw = &Pl[w][0];

    // prologue: DMA tile 0 -> buf 0
    async_copy16(&Kl[0][w * 512], ksrc);
    async_copy16(&Vl[0][w * 512], vsrc);
    if (w == 0) async_copy16(&Vl[0][2048], vsrc + 2048);
    __syncthreads();

    for (int jb = 0; jb < NJB; ++jb) {
        const int cur = jb & 1;
        if (jb + 1 < NJB) {
            const short* ks = ksrc + (size_t)(jb + 1) * KTILE_SH;
            const short* vs = vsrc + (size_t)(jb + 1) * VTILE_SH;
            async_copy16(&Kl[cur ^ 1][w * 512], ks);
            async_copy16(&Vl[cur ^ 1][w * 512], vs);
            if (w == 0) async_copy16(&Vl[cur ^ 1][2048], vs + 2048);
        }
        // K frags: [key-half kh][dh-half hh]
        const short* kl = &Kl[cur][0];
        short8 kf00 = *(const short8*)&kl[(lo) * 32 + g * 8];
        short8 kf01 = *(const short8*)&kl[1024 + (lo) * 32 + g * 8];
        short8 kf10 = *(const short8*)&kl[(16 + lo) * 32 + g * 8];
        short8 kf11 = *(const short8*)&kl[1024 + (16 + lo) * 32 + g * 8];
        // QK + exp + pack per row-group
        #pragma unroll
        for (int rg = 0; rg < 2; rg++) {
            f32x4 s0 = __builtin_amdgcn_mfma_f32_16x16x32_bf16(qa[rg][0], kf00, z, 0, 0, 0);
            s0 = __builtin_amdgcn_mfma_f32_16x16x32_bf16(qa[rg][1], kf01, s0, 0, 0, 0);
            f32x4 s1 = __builtin_amdgcn_mfma_f32_16x16x32_bf16(qa[rg][0], kf10, z, 0, 0, 0);
            s1 = __builtin_amdgcn_mfma_f32_16x16x32_bf16(qa[rg][1], kf11, s1, 0, 0, 0);
            #pragma unroll
            for (int r = 0; r < 4; r++) {
                uint32_t u0 = __float_as_uint(__builtin_amdgcn_exp2f(s0[r])) + 0x8000u;
                uint32_t u1 = __float_as_uint(__builtin_amdgcn_exp2f(s1[r])) + 0x8000u;
                pw[(rg * 16 + g * 4 + r) * PSTRD + lo] = __builtin_amdgcn_perm(u1, u0, 0x07060302u);
            }
        }
        // PV per row-group
        const short* vl = &Vl[cur][0];
        #pragma unroll
        for (int rg = 0; rg < 2; rg++) {
            u32x4 prv = *(const u32x4*)&pw[(rg * 16 + lo) * PSTRD + g * 4];
            short8 pa = __builtin_bit_cast(short8, prv);
            #pragma unroll
            for (int f = 0; f < 5; f++) {
                short8 vf = *(const short8*)&vl[(f * 16 + lo) * 32 + g * 8];
                o[rg][f] = __builtin_amdgcn_mfma_f32_16x16x32_bf16(pa, vf, o[rg][f], 0, 0, 0);
            }
        }
        __syncthreads();
    }

    short* op = ob + ((size_t)(b * N_TOK) + q0) * INNER + h * DH;
    #pragma unroll
    for (int rg = 0; rg < 2; rg++)
        for (int r = 0; r < 4; r++) {
            float l = __shfl(o[rg][4][r], lane & 48);   // col 0 of frag4 = sum(p*mask)
            float inv = (l > 0.f) ? 1.f / l : 0.f;
            short* o_ = op + (size_t)(rg * 16 + g * 4 + r) * INNER;
            o_[lo]      = f2bf(o[rg][0][r] * inv);
            o_[16 + lo] = f2bf(o[rg][1][r] * inv);
            o_[32 + lo] = f2bf(o[rg][2][r] * inv);
            o_[48 + lo] = f2bf(o[rg][3][r] * inv);
        }
}

extern "C" void kernel_launch(void* const* d_in, const int* in_sizes, int n_in,
                              void* d_out, int out_size, void* d_ws, size_t ws_size,
                              hipStream_t stream) {
    const float* x    = (const float*)d_in[0];
    const float* ctx  = (const float*)d_in[1];
    const int*   mask = (const int*)d_in[2];
    const float* Wq   = (const float*)d_in[3];
    const float* Wk   = (const float*)d_in[4];
    const float* Wv   = (const float*)d_in[5];
    const float* Wkbg = (const float*)d_in[6];
    const float* Wvbg = (const float*)d_in[7];
    const float* Wout = (const float*)d_in[8];
    const float* bout = (const float*)d_in[9];
    float* out = (float*)d_out;

    char* p = (char*)d_ws;
    auto alloc = [&](size_t b) { char* r = p; p += (b + 255) & ~(size_t)255; return r; };
    short* x_bf  = (short*)alloc((size_t)BATCH * N_TOK * QDIM * 2);
    short* c_bf  = (short*)alloc((size_t)BATCH * N_TOK * CDIM * 2);
    short* Wqt   = (short*)alloc((size_t)INNER * QDIM * 2);
    short* Wkvt  = (short*)alloc((size_t)2 * INNER * CDIM * 2);   // Wk | Wv transposed
    short* Wot   = (short*)alloc((size_t)QDIM * INNER * 2);
    short* q_bf  = (short*)alloc((size_t)BATCH * NH * N_TOK * DH * 2);
    short* k_bf  = (short*)alloc((size_t)BATCH * NH * NJB * KTILE_SH * 2);
    short* v_tmp = (short*)alloc((size_t)BATCH * NH * N1P * DH * 2);
    short* vt_bf = (short*)alloc((size_t)BATCH * NH * NJB * VTILE_SH * 2);
    short* o_bf  = (short*)alloc((size_t)BATCH * N_TOK * INNER * 2);
    float* part  = (float*)alloc((size_t)BATCH * 32 * QDIM * 4);

    const float SCALE_Q = 0.125f * 1.4426950408889634f;  // fold scale*log2(e) into Wq

    int n4 = BATCH * N_TOK * QDIM / 4;
    cast2_bf16_kernel<<<(2 * n4 + 255) / 256, 256, 0, stream>>>(x, ctx, x_bf, c_bf, n4);

    transpose_cast_kernel<<<dim3(INNER / 32, QDIM / 32), 256, 0, stream>>>(Wq, Wqt, QDIM, INNER, SCALE_Q);
    transpose_cast_kernel<<<dim3(INNER / 32, CDIM / 32), 256, 0, stream>>>(Wk, Wkvt, CDIM, INNER, 1.f);
    transpose_cast_kernel<<<dim3(INNER / 32, CDIM / 32), 256, 0, stream>>>(Wv, Wkvt + (size_t)INNER * CDIM, CDIM, INNER, 1.f);
    transpose_cast_kernel<<<dim3(QDIM / 32, INNER / 32), 256, 0, stream>>>(Wout, Wot, INNER, QDIM, 1.f);

    pool_partial_kernel<<<dim3(32, BATCH), 256, 0, stream>>>(x, part);

    qkv_gemm_kernel<<<768, 256, 0, stream>>>(x_bf, c_bf, Wqt, Wkvt, q_bf, k_bf, v_tmp);

    bg_kernel<<<dim3(BATCH, 4), 256, 0, stream>>>(part, Wkbg, Wvbg, k_bf, v_tmp);
    transpose_v_kernel<<<dim3(NJB, 1, BATCH * NH), 256, 0, stream>>>(v_tmp, vt_bf, mask);

    attn_kernel<<<512, 256, 0, stream>>>(q_bf, k_bf, vt_bf, o_bf);

    out_gemm_kernel<<<dim3(64, 8), 256, 0, stream>>>(o_bf, Wot, out, bout);
}